// Round 1
// baseline (3241.881 us; speedup 1.0000x reference)
//
#include <hip/hip_runtime.h>
#include <math.h>

#define NTHREADS 512
#define NPTS 2048
#define MSTEPS (NPTS / 64)              // 32
#define RPW 4                           // rows per wave
#define NWAVES (NTHREADS / 64)          // 8
#define ROWS_PER_BLOCK (NWAVES * RPW)   // 32
#define BLKB (NPTS / ROWS_PER_BLOCK)    // 64 blocks per batch
#define BATCH 8
#define NBLOCKS (BATCH * BLKB)          // 512
#define SINK_ITERS 20

#if __has_builtin(__builtin_amdgcn_exp2f)
#define EXP2(x) __builtin_amdgcn_exp2f(x)
#else
#define EXP2(x) exp2f(x)
#endif

static __device__ __forceinline__ float aload(const float* p) {
  return __hip_atomic_load(p, __ATOMIC_RELAXED, __HIP_MEMORY_SCOPE_AGENT);
}
static __device__ __forceinline__ unsigned aloadu(const unsigned* p) {
  return __hip_atomic_load(p, __ATOMIC_RELAXED, __HIP_MEMORY_SCOPE_AGENT);
}
static __device__ __forceinline__ void astore(float* p, float v) {
  __hip_atomic_store(p, v, __ATOMIC_RELAXED, __HIP_MEMORY_SCOPE_AGENT);
}

// Workspace layout (bytes):
//   [0..3]      float acc
//   [4..7]      uint  done
//   [8..39]     uint  bars[8]
//   [256 ..)            float F[8][2048]    (64 KB)
//   [256+64K ..)        float G[8][2048]    (64 KB)
//   [256+128K ..)       uint  CMIN[8][2048] (64 KB)  -- memset 0x7f
__global__ void __launch_bounds__(NTHREADS, 4)
sinkhorn_loss_kernel(const float* __restrict__ target,
                     const float* __restrict__ pre,
                     float* __restrict__ out,
                     unsigned char* __restrict__ ws)
{
  float*    acc  = (float*)ws;
  unsigned* done = (unsigned*)(ws + 4);
  unsigned* bars = (unsigned*)(ws + 8);
  float*    F    = (float*)(ws + 256);
  float*    G    = (float*)(ws + 256 + 4 * BATCH * NPTS);
  unsigned* CMIN = (unsigned*)(ws + 256 + 8 * BATCH * NPTS);

  __shared__ float4 lds4[NPTS];    // {y0*s, y1*s, y2*s, Gc}  32 KB
  __shared__ float  extra[NPTS];   // colmin (as uint) / Gv    8 KB

  const int tid  = threadIdx.x;
  const int wid  = tid >> 6;
  const int lane = tid & 63;
  const int b    = blockIdx.x / BLKB;
  const int bib  = blockIdx.x % BLKB;

  const float S2  = 7.21347520444482f;   // 1/(EPS*ln2)
  const float S1  = sqrtf(S2);
  const float LB2 = -11.0f;              // log2(1/2048)

  const float* tb = target + (size_t)b * NPTS * 3;
  const float* pb = pre    + (size_t)b * NPTS * 3;
  float*    Fb  = F    + b * NPTS;
  float*    Gb  = G    + b * NPTS;
  unsigned* CMb = CMIN + b * NPTS;
  unsigned* bar = bars + b;

  int gen = 0;

  // ---- per-batch monotonic barrier (64 blocks/group) ----
  auto gbar = [&]() {
    ++gen;
    __syncthreads();
    if (tid == 0) {
      __threadfence();
      atomicAdd(bar, 1u);
      const unsigned tgt = (unsigned)(gen * BLKB);
      while (aloadu(bar) < tgt) __builtin_amdgcn_s_sleep(8);
      __threadfence();
    }
    __syncthreads();
  };

  // ---- stage column side into LDS: {pts*S1, V - YY + addc}, optionally raw V ----
  auto build_lds = [&](const float* pts, const float* V, float addc, bool keepV) {
    for (int m = tid; m < NPTS; m += NTHREADS) {
      const float* p = pts + m * 3;
      float y0 = p[0] * S1, y1 = p[1] * S1, y2 = p[2] * S1;
      float yy = y0 * y0 + y1 * y1 + y2 * y2;
      float v  = V ? aload(V + m) : 0.0f;
      lds4[m] = make_float4(y0, y1, y2, v - yy + addc);
      if (keepV) extra[m] = v;
    }
  };

  const int n0 = bib * ROWS_PER_BLOCK + wid * RPW;

  auto load_rows = [&](const float* pts, float x2[RPW][3], float XX[RPW]) {
    for (int r = 0; r < RPW; ++r) {
      const float* p = pts + (n0 + r) * 3;
      float a0 = p[0] * S1, a1 = p[1] * S1, a2 = p[2] * S1;
      XX[r] = a0 * a0 + a1 * a1 + a2 * a2;
      x2[r][0] = a0 + a0; x2[r][1] = a1 + a1; x2[r][2] = a2 + a2;
    }
  };

  // ================= Chamfer pass =================
  for (int m = tid; m < NPTS; m += NTHREADS)
    ((unsigned*)extra)[m] = 0x7f800000u;          // +inf
  build_lds(tb, nullptr, 0.0f, false);            // w = -YY
  __syncthreads();
  {
    float x2[RPW][3], XX[RPW], rmax[RPW];
    load_rows(pb, x2, XX);
#pragma unroll
    for (int r = 0; r < RPW; ++r) rmax[r] = -3.0e38f;
    for (int ms = 0; ms < MSTEPS; ++ms) {
      float4 v = lds4[ms * 64 + lane];
      float cmin = 3.0e38f;
#pragma unroll
      for (int r = 0; r < RPW; ++r) {
        float t = v.w;                            // -YY
        t = fmaf(x2[r][0], v.x, t);
        t = fmaf(x2[r][1], v.y, t);
        t = fmaf(x2[r][2], v.z, t);               // t = 2xy - YY
        rmax[r] = fmaxf(rmax[r], t);
        cmin = fminf(cmin, XX[r] - t);            // C2 = XX + YY - 2xy
      }
      atomicMin((unsigned*)&extra[ms * 64 + lane], __float_as_uint(cmin));
    }
    float d1sum = 0.0f;
#pragma unroll
    for (int r = 0; r < RPW; ++r) {
      float t = rmax[r];
      for (int off = 32; off; off >>= 1) t = fmaxf(t, __shfl_xor(t, off));
      d1sum += XX[r] - t;                         // min_m C2  (weight 1.0)
    }
    if (lane == 0) atomicAdd(acc, d1sum);
    __syncthreads();
    for (int m = tid; m < NPTS; m += NTHREADS)
      atomicMin(&CMb[m], ((unsigned*)extra)[m]);
  }
  gbar();  // gen 1: CMIN complete for this batch
  if (tid < ROWS_PER_BLOCK) {
    float d2 = __uint_as_float(aloadu(&CMb[bib * ROWS_PER_BLOCK + tid]));
    atomicAdd(acc, 0.5f * d2);
  }

  // ================= Sinkhorn: 20 x (F-update, G-update) =================
  auto sink_pass = [&](const float* rowpts, float* Vout) {
    float x2[RPW][3], XX[RPW], S[RPW];
    load_rows(rowpts, x2, XX);
#pragma unroll
    for (int r = 0; r < RPW; ++r) S[r] = 0.0f;
    for (int ms = 0; ms < MSTEPS; ++ms) {
      float4 v = lds4[ms * 64 + lane];
#pragma unroll
      for (int r = 0; r < RPW; ++r) {
        float t = v.w - XX[r];                    // Gc - XX
        t = fmaf(x2[r][0], v.x, t);
        t = fmaf(x2[r][1], v.y, t);
        t = fmaf(x2[r][2], v.z, t);               // t = G - C2 + lb2
        S[r] += EXP2(t);
      }
    }
#pragma unroll
    for (int r = 0; r < RPW; ++r) {
      float s = S[r];
      for (int off = 32; off; off >>= 1) s += __shfl_xor(s, off);
      if (lane == r) astore(Vout + n0 + r, -log2f(s));
    }
  };

  for (int it = 0; it < SINK_ITERS; ++it) {
    build_lds(tb, Gb, LB2, false);   // G was memset to 0 for it==0
    __syncthreads();
    sink_pass(pb, Fb);
    gbar();
    build_lds(pb, Fb, LB2, false);
    __syncthreads();
    sink_pass(tb, Gb);
    gbar();
  }

  // ================= Final transport-cost pass =================
  build_lds(tb, Gb, 0.0f, true);     // w = G - YY, extra = G
  __syncthreads();
  {
    float x2[RPW][3], XX[RPW], A2[RPW], Ar[RPW], Sf[RPW];
    load_rows(pb, x2, XX);
#pragma unroll
    for (int r = 0; r < RPW; ++r) {
      A2[r] = aload(Fb + n0 + r);    // F[n]
      Ar[r] = A2[r] - XX[r];
      Sf[r] = 0.0f;
    }
    for (int ms = 0; ms < MSTEPS; ++ms) {
      float4 v = lds4[ms * 64 + lane];
      float gv = extra[ms * 64 + lane];
#pragma unroll
      for (int r = 0; r < RPW; ++r) {
        float u = v.w + Ar[r];                    // F + G - C2
        u = fmaf(x2[r][0], v.x, u);
        u = fmaf(x2[r][1], v.y, u);
        u = fmaf(x2[r][2], v.z, u);
        float e  = EXP2(u);
        float c2 = (A2[r] - u) + gv;              // C2 = F + G - u
        Sf[r] = fmaf(e, c2, Sf[r]);
      }
    }
    float tot = 0.0f;
#pragma unroll
    for (int r = 0; r < RPW; ++r) {
      float s = Sf[r];
      for (int off = 32; off; off >>= 1) s += __shfl_xor(s, off);
      tot += s;
    }
    if (lane == 0) atomicAdd(acc, tot);
  }

  // ================= finish =================
  __syncthreads();
  if (tid == 0) {
    __threadfence();
    atomicAdd(done, 1u);
  }
  if (blockIdx.x == 0 && tid == 0) {
    while (aloadu(done) < (unsigned)NBLOCKS) __builtin_amdgcn_s_sleep(8);
    __threadfence();
    // out = (EPS*ln2 / 2048) * [ sum d1 + 0.5 sum d2 + sum 2^u * C2 ]
    out[0] = aload(acc) * (0.13862943611198906f / 2048.0f);
  }
}

extern "C" void kernel_launch(void* const* d_in, const int* in_sizes, int n_in,
                              void* d_out, int out_size, void* d_ws, size_t ws_size,
                              hipStream_t stream) {
  const float* target = (const float*)d_in[0];
  const float* pre    = (const float*)d_in[1];
  float* out = (float*)d_out;
  unsigned char* ws = (unsigned char*)d_ws;

  const size_t fg_bytes = 256 + (size_t)8 * BATCH * NPTS;       // acc/done/bars + F + G
  hipMemsetAsync(ws, 0, fg_bytes, stream);                      // zero counters, F, G
  hipMemsetAsync(ws + fg_bytes, 0x7f, (size_t)4 * BATCH * NPTS, stream); // CMIN = big
  sinkhorn_loss_kernel<<<dim3(NBLOCKS), dim3(NTHREADS), 0, stream>>>(target, pre, out, ws);
}